// Round 8
// baseline (112.670 us; speedup 1.0000x reference)
//
#include <hip/hip_runtime.h>
#include <stdint.h>

// GPTQ 4-bit fused dequant-GEMM, MI355X gfx950.  Round 8.
// M=128, K=4096, N=11008, group=128, g_idx[k]=k>>7 (affine).
//
// R6 (VALU halving) and R7 (qweight-drain hoist) were both ~neutral: k_gemm
// stuck at ~35-40us = ~7Kcyc per barrier-iteration, unexplained by issue/
// latency arithmetic, and invisible in top-5 (harness 268MB ws-fills @42us
// dominate).  R8 is a discriminating experiment + unconditional win:
//  * NO split-K: partial buffers and k_reduce deleted (saves ~5us + 26MB
//    traffic + 1 dispatch in all worlds).  out written directly with bias.
//  * BM=64 x BN=64, BK=256 (2 GS-groups per stage), grid (172,2)=344 blocks,
//    2x32KB LDS dbuf, 16 fat iterations per block (halved barrier count).
//  * 8 waves = 2m x 2n x 2kh; kh splits kk 0..7; pair (w,w^4) merges via LDS.
// World A (throughput model right): k_gemm ~9-13us, total ~70-78us.
// World B (mystery per-iteration wall): k_gemm ~45-50us -> ENTERS top-5,
// finally yielding its counters.

#define M_DIM 128
#define K_DIM 4096
#define N_DIM 11008
#define GS    128
#define BK    256
#define NITER (K_DIM / BK)   // 16

typedef _Float16 half8  __attribute__((ext_vector_type(8)));
typedef _Float16 half2t __attribute__((ext_vector_type(2)));
typedef _Float16 half4t __attribute__((ext_vector_type(4)));
typedef float    f32x4  __attribute__((ext_vector_type(4)));

// ---------------- prep: blocks 0..511 cvt x->f16; 512..1887 zsc ----------
__global__ void k_prep(const float* __restrict__ x, const int* __restrict__ qzeros,
                       const float* __restrict__ scales,
                       _Float16* __restrict__ xh, half2t* __restrict__ zsc) {
    int b = blockIdx.x, tid = threadIdx.x;
    if (b < 512) {                                   // 512*256*4 == 524288 exact
        int i = (b * 256 + tid) * 4;
        float4 v = *(const float4*)(x + i);
        half4t o;
        o[0] = (_Float16)v.x; o[1] = (_Float16)v.y;
        o[2] = (_Float16)v.z; o[3] = (_Float16)v.w;
        *(half4t*)(xh + i) = o;
    } else {                                         // 1376 blocks: 32 g x 43 nb
        b -= 512;
        int g = b / 43;
        int n = (b - g * 43) * 256 + tid;            // 43*256 == 11008 exact
        unsigned qz = (unsigned)qzeros[g * (N_DIM / 8) + (n >> 3)];
        float z1 = (float)((qz >> ((n & 7) * 4)) & 15u) + 1.0f;
        float s  = scales[g * N_DIM + n];
        half2t o;
        o[0] = (_Float16)s;
        o[1] = (_Float16)(-z1 * s);
        zsc[g * N_DIM + n] = o;
    }
}

// async 16B/lane global->LDS; lds base wave-uniform, lane i -> base + i*16.
__device__ __forceinline__ void load_lds16(const void* g, void* l) {
    __builtin_amdgcn_global_load_lds(
        (const __attribute__((address_space(1))) unsigned int*)g,
        (__attribute__((address_space(3))) unsigned int*)l, 16, 0, 0);
}

// nibble pair p (nibbles 2p, 2p+1) of q -> two f16 weights:
//  t  = {0x6400|nib_lo, 0x6400|nib_hi<<4} = {1024+q_lo, 1024+16*q_hi}
//  qf = t - 1024                  (EXACT in f16: integers <= 2048)
//  w  = fma(qf, {s, s/16}, {-z1}) where z1 = (z+1)*s
// No pointer casts: pure vector ops, SROA-safe (scratch regression guard).
__device__ __forceinline__ half8 dequant8(unsigned q, half2t S2, half2t Z2) {
    const half2t BIAS = __builtin_bit_cast(half2t, 0x64006400u);
    half2t w[4];
#pragma unroll
    for (int p = 0; p < 4; ++p) {
        unsigned r = __builtin_amdgcn_perm(q, q, 0x00010001u * (unsigned)p); // byte p -> bytes 0,2
        unsigned t = (r & 0x00F0000Fu) | 0x64006400u;                        // v_and_or_b32
        w[p] = __builtin_elementwise_fma(__builtin_bit_cast(half2t, t) - BIAS, S2, Z2);
    }
    half4t lo = __builtin_shufflevector(w[0], w[1], 0, 1, 2, 3);
    half4t hi = __builtin_shufflevector(w[2], w[3], 0, 1, 2, 3);
    return __builtin_shufflevector(lo, hi, 0, 1, 2, 3, 4, 5, 6, 7);
}

// ---------------- main fused kernel ----------------
__global__ __launch_bounds__(512, 4)
void k_gemm(const _Float16* __restrict__ xh,     // [128][4096] f16
            const int*      __restrict__ qweight,// [512][11008] int32
            const half2t*   __restrict__ zsc,    // [32][11008] {s, -(z+1)s}
            const float*    __restrict__ bias,   // [11008]
            float*          __restrict__ out)    // [128][11008]
{
    // Double-buffered A tile: 64 m x 256 k f16 (32 KB each).
    // Row = 512 B = 32 chunks of 16 B.  Logical (m, kb) stored at physical
    // chunk (kb&16) | ((kb&15)^(m&15)); staged so chunk c = it*512+tid lands
    // at byte offset c*16 (global side carries the XOR).
    __shared__ _Float16 As[2][64 * 256];   // 2 x 32 KB

    const int tid  = threadIdx.x;
    const int lane = tid & 63;
    const int w    = tid >> 6;     // 0..7
    const int wx   = w & 1;        // n offset 32*wx
    const int wy   = (w >> 1) & 1; // m offset 32*wy
    const int kh   = w >> 2;       // kk-half: kh=0 -> kk 0..3, kh=1 -> kk 4..7
    const int q    = lane >> 4;    // quad
    const int lr   = lane & 15;

    const int n0 = blockIdx.x * 64;
    const int m0 = blockIdx.y * 64;
    int ncol[2] = { n0 + wx * 32 + lr, n0 + wx * 32 + lr + 16 };

    f32x4 acc[2][2];
#pragma unroll
    for (int f = 0; f < 2; ++f)
#pragma unroll
        for (int h = 0; h < 2; ++h)
            acc[f][h] = (f32x4){0.f, 0.f, 0.f, 0.f};

    // staging geometry: c = it*512 + tid; m = c>>5; j = c&31;
    // global kb = (j&16) | ((j&15)^(m&15)); LDS dest halfs = c*8.
    int cm[4], ckb[4];
#pragma unroll
    for (int it = 0; it < 4; ++it) {
        int c = it * 512 + tid;
        cm[it] = c >> 5;
        int j  = c & 31;
        ckb[it] = (j & 16) | ((j & 15) ^ (cm[it] & 15));
    }
    const int wave_lds = w * 512;   // halfs; + it*4096 per chunk-batch

    // ---- prologue: prime buffer 0, qweight/zsc for iter 0, bias ----
#pragma unroll
    for (int it = 0; it < 4; ++it)
        load_lds16(xh + (size_t)(m0 + cm[it]) * K_DIM + ckb[it] * 8,
                   &As[0][it * 4096 + wave_lds]);
    unsigned qwn[8];
    half2t   zsn[2];
#pragma unroll
    for (int t = 0; t < 4; ++t)
#pragma unroll
        for (int h = 0; h < 2; ++h)
            qwn[t * 2 + h] = (unsigned)qweight[(size_t)((kh * 4 + t) * 4 + q) * N_DIM + ncol[h]];
#pragma unroll
    for (int h = 0; h < 2; ++h) zsn[h] = zsc[(size_t)kh * N_DIM + ncol[h]];
    float bv[2] = { bias[ncol[0]], bias[ncol[1]] };

#pragma unroll 2
    for (int i = 0; i < NITER; ++i) {
        unsigned qw[8];
        half2t   zs[2];
#pragma unroll
        for (int j = 0; j < 8; ++j) qw[j] = qwn[j];
#pragma unroll
        for (int h = 0; h < 2; ++h) zs[h] = zsn[h];

        __syncthreads();   // A(i) resident in As[i&1]

        if (i + 1 < NITER) {  // next stage + next B data, in flight under compute
#pragma unroll
            for (int it = 0; it < 4; ++it)
                load_lds16(xh + (size_t)(m0 + cm[it]) * K_DIM + (i + 1) * BK + ckb[it] * 8,
                           &As[(i + 1) & 1][it * 4096 + wave_lds]);
#pragma unroll
            for (int t = 0; t < 4; ++t)
#pragma unroll
                for (int h = 0; h < 2; ++h)
                    qwn[t * 2 + h] = (unsigned)qweight[(size_t)((i + 1) * 32 + (kh * 4 + t) * 4 + q) * N_DIM + ncol[h]];
#pragma unroll
            for (int h = 0; h < 2; ++h)
                zsn[h] = zsc[(size_t)(2 * (i + 1) + kh) * N_DIM + ncol[h]];
        }

        // S2={s, s/16}, Z2={-z1,-z1} from packed zs
        const half2t SC = { (_Float16)1.0f, (_Float16)0.0625f };
        half2t S2[2], Z2[2];
#pragma unroll
        for (int h = 0; h < 2; ++h) {
            half2t ss = __builtin_shufflevector(zs[h], zs[h], 0, 0);
            S2[h] = ss * SC;
            Z2[h] = __builtin_shufflevector(zs[h], zs[h], 1, 1);
        }

#pragma unroll
        for (int t = 0; t < 4; ++t) {
            const int kk = kh * 4 + t;
            half8 bf[2];
#pragma unroll
            for (int h = 0; h < 2; ++h)
                bf[h] = dequant8(qw[t * 2 + h], S2[h], Z2[h]);
#pragma unroll
            for (int f = 0; f < 2; ++f) {
                int m    = wy * 32 + f * 16 + lr;
                int kb2  = kk * 4 + q;
                int phys = (kb2 & 16) | ((kb2 & 15) ^ lr);   // m&15 == lr
                half8 af = *(const half8*)(&As[i & 1][m * 256 + phys * 8]);
#pragma unroll
                for (int h = 0; h < 2; ++h)
                    acc[f][h] = __builtin_amdgcn_mfma_f32_16x16x32_f16(af, bf[h], acc[f][h], 0, 0, 0);
            }
        }
    }

    // ---- pair reduction (w, w^4) through LDS, then direct out+bias ----
    __syncthreads();                       // all A reads done; LDS reusable
    float* red = (float*)&As[0][0];        // 32 KB: 4 pairs x 8 KB
    const int pid = w & 3;
    if (kh == 1) {
#pragma unroll
        for (int f = 0; f < 2; ++f)
#pragma unroll
            for (int h = 0; h < 2; ++h)
                *(f32x4*)(red + pid * 2048 + (f * 2 + h) * 256 + lane * 4) = acc[f][h];
    }
    __syncthreads();
    if (kh == 0) {
#pragma unroll
        for (int f = 0; f < 2; ++f) {
            int mrow = m0 + wy * 32 + f * 16 + q * 4;
#pragma unroll
            for (int h = 0; h < 2; ++h) {
                f32x4 o = acc[f][h] + *(const f32x4*)(red + pid * 2048 + (f * 2 + h) * 256 + lane * 4);
#pragma unroll
                for (int r = 0; r < 4; ++r)
                    out[(size_t)(mrow + r) * N_DIM + ncol[h]] = o[r] + bv[h];
            }
        }
    }
}

extern "C" void kernel_launch(void* const* d_in, const int* in_sizes, int n_in,
                              void* d_out, int out_size, void* d_ws, size_t ws_size,
                              hipStream_t stream) {
    const float* x       = (const float*)d_in[0];
    const int*   qweight = (const int*)d_in[1];
    const int*   qzeros  = (const int*)d_in[2];
    const float* scales  = (const float*)d_in[3];
    const float* bias    = (const float*)d_in[4];
    // d_in[5] = g_idx, affine by construction -> unused

    char* ws = (char*)d_ws;
    _Float16* xh  = (_Float16*)ws;             // 1,048,576 B
    half2t*   zsc = (half2t*)(ws + 1048576);   // 1,409,024 B

    k_prep<<<dim3(1888),    dim3(256), 0, stream>>>(x, qzeros, scales, xh, zsc);
    k_gemm<<<dim3(172, 2),  dim3(512), 0, stream>>>(xh, qweight, zsc, bias, (float*)d_out);
}

// Round 10
// 110.258 us; speedup vs baseline: 1.0219x; 1.0219x over previous
//
#include <hip/hip_runtime.h>
#include <stdint.h>

// GPTQ 4-bit fused dequant-GEMM, MI355X gfx950.  Round 10 (= R9 + typo fix:
// dequant8's shuffle intermediates are half4t, not half2t).
// M=128, K=4096, N=11008, group=128, g_idx[k]=k>>7 (affine).
//
// R5-R8 forensics: k_gemm time tracks total bytes staged through
// global_load_lds (~4.4 TB/s effective) -- invariant to barrier count (R8),
// VALU cut (R6), HBM-load hoisting (R7).  R9/R10 deletes the mechanism:
//  * k_prep pre-swizzles x into MFMA-fragment-major xf[m_tile][k_blk][lane]
//    (16B/lane): a wave's A-fragment = ONE coalesced 16B/lane global load,
//    L2-resident (xf = 1 MB, hot in every XCD L2).
//  * k_gemm: NO LDS, NO __syncthreads, NO global_load_lds.  Block = 256 thr,
//    4 waves stacked in m (wave = 32m x 64n, block = 128m x 64n), grid
//    (172, SPLIT=4) = 688 blocks, ~5 blocks/CU co-resident, per-step register
//    prefetch.  Per block-step: 32 MFMA (~155 CU-cyc) vs ~140 VALU-cyc/SIMD.
//  * split-K partials (f32, ws) + k_reduce(bias) as in R7.

#define M_DIM 128
#define K_DIM 4096
#define N_DIM 11008
#define GS    128
#define SPLIT 4
#define STEPS 32                 // k32 steps per block = K/SPLIT/32
#define PART_STRIDE ((size_t)M_DIM * N_DIM)

typedef _Float16 half8  __attribute__((ext_vector_type(8)));
typedef _Float16 half4t __attribute__((ext_vector_type(4)));
typedef _Float16 half2t __attribute__((ext_vector_type(2)));
typedef float    f32x4  __attribute__((ext_vector_type(4)));

// ---- prep: blocks 0..255 build xf (fragment-major A); 256..1631 build zsc --
// xf slot layout: slot = (m_tile*128 + k_blk)*64 + lane; 8 halfs per slot;
// element j of slot = x[m_tile*16 + (lane&15)][k_blk*32 + (lane>>4)*8 + j].
__global__ void k_prep(const float* __restrict__ x, const int* __restrict__ qzeros,
                       const float* __restrict__ scales,
                       _Float16* __restrict__ xf, half2t* __restrict__ zsc) {
    int b = blockIdx.x, t = threadIdx.x;
    if (b < 256) {                                   // 256*256 = 65536 slots exact
        int slot = b * 256 + t;
        int lane = slot & 63;
        int pair = slot >> 6;                        // m_tile*128 + k_blk
        int mt = pair >> 7, kb = pair & 127;
        int row = mt * 16 + (lane & 15);
        int col = kb * 32 + (lane >> 4) * 8;
        const float* px = x + (size_t)row * K_DIM + col;
        float4 v0 = *(const float4*)px;
        float4 v1 = *(const float4*)(px + 4);
        half8 o;
        o[0] = (_Float16)v0.x; o[1] = (_Float16)v0.y;
        o[2] = (_Float16)v0.z; o[3] = (_Float16)v0.w;
        o[4] = (_Float16)v1.x; o[5] = (_Float16)v1.y;
        o[6] = (_Float16)v1.z; o[7] = (_Float16)v1.w;
        *(half8*)(xf + (size_t)slot * 8) = o;
    } else {                                         // 1376 blocks: 32 g x 43 nb
        b -= 256;
        int g = b / 43;
        int n = (b - g * 43) * 256 + t;              // 43*256 == 11008 exact
        unsigned qz = (unsigned)qzeros[g * (N_DIM / 8) + (n >> 3)];
        float z1 = (float)((qz >> ((n & 7) * 4)) & 15u) + 1.0f;
        float s  = scales[g * N_DIM + n];
        half2t o;
        o[0] = (_Float16)s;
        o[1] = (_Float16)(-z1 * s);
        zsc[g * N_DIM + n] = o;
    }
}

// nibble pair p (nibbles 2p, 2p+1) of q -> two f16 weights:
//  t  = {0x6400|nib_lo, 0x6400|nib_hi<<4} = {1024+q_lo, 1024+16*q_hi}
//  qf = t - 1024                  (EXACT in f16: integers <= 2048)
//  w  = fma(qf, {s, s/16}, {-z1}) where z1 = (z+1)*s
// No pointer casts: pure vector ops, SROA-safe (scratch regression guard).
__device__ __forceinline__ half8 dequant8(unsigned q, half2t S2, half2t Z2) {
    const half2t BIAS = __builtin_bit_cast(half2t, 0x64006400u);
    half2t w[4];
#pragma unroll
    for (int p = 0; p < 4; ++p) {
        unsigned r = __builtin_amdgcn_perm(q, q, 0x00010001u * (unsigned)p); // byte p -> bytes 0,2
        unsigned t = (r & 0x00F0000Fu) | 0x64006400u;                        // v_and_or_b32
        w[p] = __builtin_elementwise_fma(__builtin_bit_cast(half2t, t) - BIAS, S2, Z2);
    }
    half4t w01 = __builtin_shufflevector(w[0], w[1], 0, 1, 2, 3);
    half4t w23 = __builtin_shufflevector(w[2], w[3], 0, 1, 2, 3);
    return __builtin_shufflevector(w01, w23, 0, 1, 2, 3, 4, 5, 6, 7);
}

// ---------------- main fused kernel: no LDS, no barriers ----------------
__global__ __launch_bounds__(256, 4)
void k_gemm(const _Float16* __restrict__ xf,     // fragment-major A (1 MB)
            const int*      __restrict__ qweight,// [512][11008] int32
            const half2t*   __restrict__ zsc,    // [32][11008] {s, -(z+1)s}
            float*          __restrict__ part)   // [SPLIT][128][11008]
{
    const int tid  = threadIdx.x;
    const int lane = tid & 63;
    const int w    = tid >> 6;     // 0..3: m_tiles {2w, 2w+1}
    const int q    = lane >> 4;
    const int lr   = lane & 15;

    const int n0 = blockIdx.x * 64;
    const int by = blockIdx.y;     // k-split: k0 = by*1024

    int ncol[4];
#pragma unroll
    for (int j = 0; j < 4; ++j) ncol[j] = n0 + j * 16 + lr;

    f32x4 acc[2][4];
#pragma unroll
    for (int f = 0; f < 2; ++f)
#pragma unroll
        for (int j = 0; j < 4; ++j)
            acc[f][j] = (f32x4){0.f, 0.f, 0.f, 0.f};

    // A-frag pointers: frag(mt, k_blk) at xf + (mt*128 + k_blk)*512 + lane*8
    const _Float16* pa0 = xf + (((size_t)(2 * w) * 128 + by * 32) << 9) + lane * 8;
    const _Float16* pa1 = pa0 + ((size_t)128 << 9);
    // qweight: row(s,q) = by*128 + s*4 + q
    const int* pq = qweight + (size_t)(by * 128 + q) * N_DIM;
    // zsc: group g = by*8 + gg
    const half2t* pz = zsc + (size_t)(by * 8) * N_DIM;

    // ---- prologue: s=0 A/Q, g=0 Z ----
    half8 a0 = *(const half8*)pa0;
    half8 a1 = *(const half8*)pa1;
    unsigned qc[4];
    half2t   zc[4];
#pragma unroll
    for (int j = 0; j < 4; ++j) {
        qc[j] = (unsigned)pq[ncol[j]];
        zc[j] = pz[ncol[j]];
    }

    for (int g = 0; g < 8; ++g) {
        // group constants: S2={s, s/16}, Z2={-z1,-z1}
        const half2t SC = { (_Float16)1.0f, (_Float16)0.0625f };
        half2t S2[4], Z2[4];
#pragma unroll
        for (int j = 0; j < 4; ++j) {
            half2t ss = __builtin_shufflevector(zc[j], zc[j], 0, 0);
            S2[j] = ss * SC;
            Z2[j] = __builtin_shufflevector(zc[j], zc[j], 1, 1);
        }

#pragma unroll
        for (int t = 0; t < 4; ++t) {
            const int s  = g * 4 + t;
            const int sn = (s + 1 < STEPS) ? s + 1 : s;   // wave-uniform clamp

            // ---- issue next step's loads (in flight under compute) ----
            half8 na0 = *(const half8*)(pa0 + (size_t)sn * 512);
            half8 na1 = *(const half8*)(pa1 + (size_t)sn * 512);
            unsigned nq[4];
#pragma unroll
            for (int j = 0; j < 4; ++j)
                nq[j] = (unsigned)pq[(size_t)sn * 4 * N_DIM + ncol[j]];
            half2t nz[4];
            if (t == 3) {
                int gn = (g + 1 < 8) ? g + 1 : g;
#pragma unroll
                for (int j = 0; j < 4; ++j)
                    nz[j] = pz[(size_t)gn * N_DIM + ncol[j]];
            }

            // ---- compute current step ----
#pragma unroll
            for (int j = 0; j < 4; ++j) {
                half8 bf = dequant8(qc[j], S2[j], Z2[j]);
                acc[0][j] = __builtin_amdgcn_mfma_f32_16x16x32_f16(a0, bf, acc[0][j], 0, 0, 0);
                acc[1][j] = __builtin_amdgcn_mfma_f32_16x16x32_f16(a1, bf, acc[1][j], 0, 0, 0);
            }

            // rotate
            a0 = na0; a1 = na1;
#pragma unroll
            for (int j = 0; j < 4; ++j) qc[j] = nq[j];
            if (t == 3) {
#pragma unroll
                for (int j = 0; j < 4; ++j) zc[j] = nz[j];
            }
        }
    }

    // ---- epilogue: coalesced partial stores (D: row=q*4+r, col=lr) ----
    float* po = part + (size_t)by * PART_STRIDE;
#pragma unroll
    for (int f = 0; f < 2; ++f) {
        int mrow = w * 32 + f * 16 + q * 4;
#pragma unroll
        for (int j = 0; j < 4; ++j)
#pragma unroll
            for (int r = 0; r < 4; ++r)
                po[(size_t)(mrow + r) * N_DIM + ncol[j]] = acc[f][j][r];
    }
}

// ---------------- reduce: out = bias + sum_s part[s] ----------------
__global__ void k_reduce(const float* __restrict__ part, const float* __restrict__ bias,
                         float* __restrict__ out) {
    int i = (blockIdx.x * 256 + threadIdx.x) * 4;   // 1376 blocks: 128*11008 exact
    int m = i / N_DIM;
    int n = i - m * N_DIM;                           // N_DIM%4==0 -> n%4==0
    f32x4 s = *(const f32x4*)(bias + n);
#pragma unroll
    for (int sp = 0; sp < SPLIT; ++sp)
        s += *(const f32x4*)(part + sp * PART_STRIDE + i);
    *(f32x4*)(out + i) = s;
}

extern "C" void kernel_launch(void* const* d_in, const int* in_sizes, int n_in,
                              void* d_out, int out_size, void* d_ws, size_t ws_size,
                              hipStream_t stream) {
    const float* x       = (const float*)d_in[0];
    const int*   qweight = (const int*)d_in[1];
    const int*   qzeros  = (const int*)d_in[2];
    const float* scales  = (const float*)d_in[3];
    const float* bias    = (const float*)d_in[4];
    // d_in[5] = g_idx, affine by construction -> unused

    char* ws = (char*)d_ws;
    _Float16* xf   = (_Float16*)ws;                              // 1,048,576 B
    half2t*   zsc  = (half2t*)(ws + 1048576);                    // 1,409,024 B
    float*    part = (float*)(ws + 1048576 + 1409024);           // 4 x 5,636,096 B

    k_prep  <<<dim3(1632),            dim3(256), 0, stream>>>(x, qzeros, scales, xf, zsc);
    k_gemm  <<<dim3(N_DIM/64, SPLIT), dim3(256), 0, stream>>>(xf, qweight, zsc, part);
    k_reduce<<<dim3(1376),            dim3(256), 0, stream>>>(part, bias, (float*)d_out);
}